// Round 12
// baseline (2502.904 us; speedup 1.0000x reference)
//
#include <hip/hip_runtime.h>
#include <hip/hip_bf16.h>
#include <stdint.h>

// GNN_758: stacked RelGraphConv x2.  N=50000, E=1.6M, D=128, R=20.
// agg[dst] = sum_r (sum_{e in rel r -> dst} h[src]) @ W[r]; self-loop = rel 20.
// R19: flat divergence-free phase 1 via STANDARD f32 LDS atomics (R16's idea,
// verifiable instrument). Thread = (edge x 16B slice): decode (src,dd,rl),
// one half8 load, 8x atomicAdd(ds_add_f32) into Sf[dd*644 + rl*128 + f]
// (stride 644 -> ~4-way banks). Phase 2 reads 2x float4 + v_cvt_pkrtz -> f16
// fragment (same lane semantics as R15-18 -> MFMA unchanged). Self-loop =
// direct global A-fragment. Cell sums now f32 (better than f16 chain).
// tile_sort becomes r-major (sub = r*16+dd) + emits ec = dd<<3|rl (u8) so
// chunk ranges are contiguous; chunk bounds = cofs[tile*320 + 80c].
// Prep otherwise = R18 (cnt / wave-per-bin colscan / scan1 / scatter).

#define NN 50000
#define NE 1600000
#define DIM 128
#define NREL 20
#define NRELP 21
#define TILE 16
#define NTILE (NN / TILE)          // 3125 = tile bins
#define CELLS (NN * NREL)
#define CHB 256                    // chunk blocks for count/scatter
#define CHE (NE / CHB)             // 6250 edges per chunk block
#define SPK_CAP 1024               // staged payloads per block (mean 512)
#define PACKED_ELEMS (2 * NRELP * 4 * 8 * 64 * 8)    // 688128

typedef __attribute__((ext_vector_type(8))) short short8;
typedef __attribute__((ext_vector_type(8))) _Float16 half8;
typedef __attribute__((ext_vector_type(4))) float f32x4;

__device__ __forceinline__ unsigned short f32_to_f16_raw(float f) {
  union { _Float16 h; unsigned short u; } c;
  c.h = (_Float16)f;               // v_cvt_f16_f32 (RNE)
  return c.u;
}
__device__ __forceinline__ unsigned cvt_pkrtz(float a, float b) {
  unsigned r;                      // 2 f32 -> packed 2 f16 (RTZ), gfx6+ VOP3
  asm("v_cvt_pkrtz_f16_f32 %0, %1, %2" : "=v"(r) : "v"(a), "v"(b));
  return r;
}

// ---------------- fp32 -> f16 (x4), nontemporal stores ----------------
__global__ void cvt_f16_kernel(const float* __restrict__ in,
                               unsigned short* __restrict__ out, int n4) {
  int i = blockIdx.x * 256 + threadIdx.x;
  if (i < n4) {
    float4 f = ((const float4*)in)[i];
    unsigned long long p =
        (unsigned long long)f32_to_f16_raw(f.x)
      | ((unsigned long long)f32_to_f16_raw(f.y) << 16)
      | ((unsigned long long)f32_to_f16_raw(f.z) << 32)
      | ((unsigned long long)f32_to_f16_raw(f.w) << 48);
    __builtin_nontemporal_store(p, (unsigned long long*)out + i);  // clean -> L3
  }
}

// ---------------- pack W (+loop_w as rel 20) into B-fragment order ----------------
// WP flat: ((((l*21 + r)*4 + ks)*8 + nc)*64 + lane)*8  (verified R0/R1), f16
__global__ void pack_w_kernel(const float* __restrict__ W,
                              const float* __restrict__ loop_w,
                              unsigned short* __restrict__ WP) {
  int idx = blockIdx.x * 256 + threadIdx.x;
  if (idx >= PACKED_ELEMS) return;
  int j = idx & 7;       int t = idx >> 3;
  int lane = t & 63;     t >>= 6;
  int nc = t & 7;        t >>= 3;
  int ks = t & 3;        t >>= 2;
  int r = t % NRELP;     int l = t / NRELP;
  int k = ks * 32 + (lane >> 4) * 8 + j;
  int n = nc * 16 + (lane & 15);
  float v = (r < NREL) ? W[(((size_t)l * NREL + r) * DIM + k) * DIM + n]
                       : loop_w[((size_t)l * DIM + k) * DIM + n];
  WP[idx] = f32_to_f16_raw(v);
}

// ---------------- tile counting sort, all global accesses coalesced ----------------
__global__ __launch_bounds__(256) void cnt_kernel(
    const int* __restrict__ dst, unsigned int* __restrict__ cnt) {
  __shared__ unsigned int h[NTILE];              // 12.5 KB
  for (int i = threadIdx.x; i < NTILE; i += 256) h[i] = 0u;
  __syncthreads();
  const int base = blockIdx.x * CHE;
  for (int i = base + threadIdx.x; i < base + CHE; i += 256)
    atomicAdd(&h[dst[i] >> 4], 1u);              // LDS atomic
  __syncthreads();
  unsigned int* row = cnt + (size_t)blockIdx.x * NTILE;
  for (int i = threadIdx.x; i < NTILE; i += 256) row[i] = h[i];
}

// wave-per-bin exclusive prefix over the 256 chunk-blocks (in place) + totals.
__global__ __launch_bounds__(256) void colscan_kernel(
    unsigned int* __restrict__ cnt, unsigned int* __restrict__ csum) {
  const int b = (blockIdx.x * 256 + threadIdx.x) >> 6;   // bin = wave id
  const int lane = threadIdx.x & 63;
  if (b >= NTILE) return;
  unsigned int v[4], p[4], s = 0;
#pragma unroll
  for (int i = 0; i < 4; ++i) {
    v[i] = cnt[(size_t)(lane * 4 + i) * NTILE + b];
    p[i] = s; s += v[i];
  }
  unsigned int run = s;
  for (int d = 1; d < 64; d <<= 1) {
    unsigned int t = __shfl_up(run, d);
    if (lane >= d) run += t;
  }
  const unsigned int excl = run - s;
#pragma unroll
  for (int i = 0; i < 4; ++i)
    cnt[(size_t)(lane * 4 + i) * NTILE + b] = excl + p[i];
  if (lane == 63) csum[b] = run;
}

// single-block exclusive scan of csum[NTILE] -> starts[NTILE+1] (sentinel=NE)
__global__ __launch_bounds__(1024) void scan1_kernel(
    const unsigned int* __restrict__ csum, unsigned int* __restrict__ starts) {
  __shared__ unsigned int buf[1024];
  const int t = threadIdx.x;
  const int base = t * 4;
  unsigned int v[4], p[4], s = 0;
#pragma unroll
  for (int j = 0; j < 4; ++j) {
    v[j] = (base + j < NTILE) ? csum[base + j] : 0u;
    p[j] = s; s += v[j];
  }
  buf[t] = s;
  __syncthreads();
  for (int d = 1; d < 1024; d <<= 1) {
    unsigned int a = (t >= d) ? buf[t - d] : 0u;
    __syncthreads();
    buf[t] += a;
    __syncthreads();
  }
  unsigned int excl = buf[t] - s;
#pragma unroll
  for (int j = 0; j < 4; ++j)
    if (base + j < NTILE) starts[base + j] = excl + p[j];
  if (t == 1023) starts[NTILE] = buf[1023];      // = NE
}

// scatter to tile-sorted position. payload = src | dd<<16 | rel<<20 (5 bits).
__global__ __launch_bounds__(256) void scatter_kernel(
    const int* __restrict__ src, const int* __restrict__ dst,
    const int* __restrict__ et, const unsigned int* __restrict__ starts,
    const unsigned int* __restrict__ cnt, unsigned int* __restrict__ ep) {
  __shared__ unsigned int cur[NTILE];            // 12.5 KB
  const unsigned int* row = cnt + (size_t)blockIdx.x * NTILE;
  for (int i = threadIdx.x; i < NTILE; i += 256)
    cur[i] = starts[i] + row[i];
  __syncthreads();
  const int base = blockIdx.x * CHE;
  for (int i = base + threadIdx.x; i < base + CHE; i += 256) {
    int d = dst[i];
    unsigned int pos = atomicAdd(&cur[d >> 4], 1u);   // LDS atomic
    ep[pos] = (unsigned int)src[i] | ((unsigned int)(d & 15) << 16)
            | ((unsigned int)et[i] << 20);
  }
}

// per-tile 320-bin sort, R-MAJOR cells (sub = r*16+dd) -> cofs + es + ec.
// ec = dd<<3 | (r%5): the layer's flat phase decodes (dd, rl) per edge.
__global__ __launch_bounds__(512) void tile_sort_kernel(
    const unsigned int* __restrict__ ep, const unsigned int* __restrict__ starts,
    unsigned short* __restrict__ es, unsigned char* __restrict__ ec,
    unsigned int* __restrict__ cofs) {
  __shared__ unsigned int hist[512];             // 320 bins, padded for scan
  const int t = threadIdx.x;
  const int tile = blockIdx.x;
  const unsigned int start = starts[tile];
  const unsigned int end = starts[tile + 1];
  const int cnt = (int)(end - start);
  hist[t] = 0u;
  __syncthreads();
  for (int i = t; i < cnt; i += 512) {
    unsigned int p = ep[start + i];
    atomicAdd(&hist[(p >> 20) * 16u + ((p >> 16) & 15u)], 1u);
  }
  __syncthreads();
  unsigned int own = hist[t];
  for (int d = 1; d < 512; d <<= 1) {
    __syncthreads();
    unsigned int a = (t >= d) ? hist[t - d] : 0u;
    __syncthreads();
    hist[t] += a;
  }
  __syncthreads();
  unsigned int excl = hist[t] - own;
  hist[t] = excl;                        // becomes rank cursor
  if (t < 320) cofs[(size_t)tile * 320 + t] = start + excl;
  if (tile == NTILE - 1 && t == 0) cofs[CELLS] = (unsigned int)NE;
  __syncthreads();
  for (int i = t; i < cnt; i += 512) {
    unsigned int p = ep[start + i];
    unsigned int r = p >> 20;
    int sub = (int)(r * 16u + ((p >> 16) & 15u));
    unsigned int rk = atomicAdd(&hist[sub], 1u);
    es[start + rk] = (unsigned short)(p & 0xffffu);
    ec[start + rk] = (unsigned char)((((p >> 16) & 15u) << 3) | (r % 5u));
  }
}

// ---------------- fused RGCN layer (flat f32-atomic phase 1) ----------------
// 3125 blocks x 512 threads (8 waves). LDS ~44.3KB -> 3 blocks/CU (24 waves).
__global__ __launch_bounds__(512, 6) void rgcn_layer_kernel(
    const unsigned short* __restrict__ hb,    // [N,128] f16
    const unsigned short* __restrict__ WP,    // packed weights, f16
    const float* __restrict__ bias,           // [128] this layer
    int layer,
    const unsigned int* __restrict__ cofs,    // [CELLS+1] r-major cell offsets
    const unsigned short* __restrict__ es,    // [E] srcs, cell-sorted
    const unsigned char* __restrict__ ec,     // [E] dd<<3|rl
    float* __restrict__ outf,                 // fp32 out (layer 1) or null
    unsigned short* __restrict__ outb)        // f16 out (layer 0) or null
{
  // Sf[dd][rl*128 + f], stride 644 f32 (16B-aligned, banks spread by dd*4).
  __shared__ __align__(16) float Sf[16 * 644];   // 41216 B
  __shared__ unsigned int cofs5[5];
  __shared__ unsigned short spk[SPK_CAP];        // 2048 B
  __shared__ unsigned char sec[SPK_CAP];         // 1024 B

  const int tid  = threadIdx.x;
  const int lane = tid & 63;
  const int w    = tid >> 6;        // wave 0..7 = output col tile
  const int quad = lane >> 4;
  const int m    = lane & 15;
  const int dst_base = blockIdx.x * TILE;

  if (tid < 5) cofs5[tid] = cofs[(size_t)blockIdx.x * 320 + tid * 80];
  for (int i = tid; i < 2576; i += 512) ((float4*)Sf)[i] = (float4){0.f,0.f,0.f,0.f};
  __syncthreads();
  const int b0 = (int)cofs5[0];
  const int etot = (int)cofs5[4] - b0;
  const bool use_lds = (etot <= SPK_CAP);
  if (use_lds)
    for (int i = tid; i < etot; i += 512) { spk[i] = es[b0 + i]; sec[i] = ec[b0 + i]; }
  __syncthreads();

  f32x4 acc = (f32x4){0.f, 0.f, 0.f, 0.f};

  for (int c = 0; c < 4; ++c) {
    // ---- phase 1: flat item loop, item = (edge, 16B slice). no divergence ----
    const int begI = ((int)cofs5[c] - b0) * 16;
    const int endI = ((int)cofs5[c + 1] - b0) * 16;
    for (int idx = begI + tid; idx < endI; idx += 1024) {
      const int idx2 = idx + 512;
      const bool h2 = idx2 < endI;
      const int eA = idx >> 4,  chA = idx & 15;
      const int eB = h2 ? (idx2 >> 4) : eA;
      const int chB = h2 ? (idx2 & 15) : chA;
      int sA, cA, sB, cB;
      if (use_lds) { sA = spk[eA]; cA = sec[eA]; sB = spk[eB]; cB = sec[eB]; }
      else         { sA = es[b0 + eA]; cA = ec[b0 + eA];
                     sB = es[b0 + eB]; cB = ec[b0 + eB]; }
      half8 hA = *(const half8*)(hb + (size_t)sA * DIM + chA * 8);
      half8 hB = *(const half8*)(hb + (size_t)sB * DIM + chB * 8);
      float* pa = &Sf[(cA >> 3) * 644 + (cA & 7) * 128 + chA * 8];
#pragma unroll
      for (int j = 0; j < 8; ++j) atomicAdd(pa + j, (float)hA[j]);
      if (h2) {
        float* pb = &Sf[(cB >> 3) * 644 + (cB & 7) * 128 + chB * 8];
#pragma unroll
        for (int j = 0; j < 8; ++j) atomicAdd(pb + j, (float)hB[j]);
      }
    }
    __syncthreads();

    // ---- phase 2: nc-split 8 ways; fragment = 2x float4 + pkrtz ----
    for (int rl2 = 0; rl2 < 5; ++rl2) {
      const int r = c * 5 + rl2;
      const unsigned short* bp =
          WP + ((((size_t)(layer * NRELP + r) * 4) * 8 + w) * 64 + lane) * 8;
#pragma unroll
      for (int ks = 0; ks < 4; ++ks) {
        const float* ap = &Sf[m * 644 + rl2 * 128 + (ks * 4 + quad) * 8];
        float4 f0 = *(const float4*)ap;
        float4 f1 = *(const float4*)(ap + 4);
        half8 bv = *(const half8*)(bp + (size_t)ks * 4096);
        union { unsigned u[4]; half8 h; } av;
        av.u[0] = cvt_pkrtz(f0.x, f0.y);
        av.u[1] = cvt_pkrtz(f0.z, f0.w);
        av.u[2] = cvt_pkrtz(f1.x, f1.y);
        av.u[3] = cvt_pkrtz(f1.z, f1.w);
        acc = __builtin_amdgcn_mfma_f32_16x16x32_f16(av.h, bv, acc, 0, 0, 0);
      }
    }
    __syncthreads();

    // ---- re-zero for next atomic chunk ----
    if (c < 3) {
      for (int i = tid; i < 2576; i += 512) ((float4*)Sf)[i] = (float4){0.f,0.f,0.f,0.f};
      __syncthreads();
    }
  }

  // ---- self-loop (rel 20): A-fragment direct from global (own rows) ----
  {
    const unsigned short* bp =
        WP + ((((size_t)(layer * NRELP + NREL) * 4) * 8 + w) * 64 + lane) * 8;
#pragma unroll
    for (int ks = 0; ks < 4; ++ks) {
      half8 av = *(const half8*)(hb + (size_t)(dst_base + m) * DIM + (ks * 4 + quad) * 8);
      half8 bv = *(const half8*)(bp + (size_t)ks * 4096);
      acc = __builtin_amdgcn_mfma_f32_16x16x32_f16(av, bv, acc, 0, 0, 0);
    }
  }

  // ---- epilogue: wave w stores its 16-col tile ----
  const int col = w * 16 + m;
  const float bv = bias[col];
  if (outb) {
#pragma unroll
    for (int i = 0; i < 4; ++i)
      outb[(size_t)(dst_base + quad * 4 + i) * DIM + col] =
          f32_to_f16_raw(acc[i] + bv);
  } else {
#pragma unroll
    for (int i = 0; i < 4; ++i)
      outf[(size_t)(dst_base + quad * 4 + i) * DIM + col] = acc[i] + bv;
  }
}

// ---------------- launch ----------------
extern "C" void kernel_launch(void* const* d_in, const int* in_sizes, int n_in,
                              void* d_out, int out_size, void* d_ws, size_t ws_size,
                              hipStream_t stream) {
  const float* h0     = (const float*)d_in[0];
  const float* W      = (const float*)d_in[1];
  const float* loop_w = (const float*)d_in[2];
  const float* bias   = (const float*)d_in[3];
  const int* esrc     = (const int*)d_in[4];
  const int* edst     = (const int*)d_in[5];
  const int* etyp     = (const int*)d_in[6];
  float* out = (float*)d_out;

  char* ws = (char*)d_ws;
  size_t off = 0;
  auto alloc = [&](size_t bytes) -> void* {
    void* p = ws + off;
    off = (off + bytes + 255) & ~(size_t)255;
    return p;
  };
  unsigned short* hb0   = (unsigned short*)alloc((size_t)NN * DIM * 2);   // 12.8 MB
  unsigned short* hb1   = (unsigned short*)alloc((size_t)NN * DIM * 2);   // 12.8 MB
  unsigned short* WP    = (unsigned short*)alloc((size_t)PACKED_ELEMS * 2);
  unsigned int*   cnt   = (unsigned int*)alloc((size_t)CHB * NTILE * 4);  // 3.2 MB
  unsigned int*   csum  = (unsigned int*)alloc((size_t)NTILE * 4);
  unsigned int*   starts= (unsigned int*)alloc((size_t)(NTILE + 1) * 4);
  unsigned int*   ep    = (unsigned int*)alloc((size_t)NE * 4);           // 6.4 MB
  unsigned int*   cofs  = (unsigned int*)alloc((size_t)(CELLS + 1) * 4);  // 4 MB
  unsigned short* es    = (unsigned short*)alloc((size_t)NE * 2);         // 3.2 MB
  unsigned char*  ec    = (unsigned char*)alloc((size_t)NE);              // 1.6 MB

  cnt_kernel<<<CHB, 256, 0, stream>>>(edst, cnt);
  colscan_kernel<<<(NTILE * 64 + 255) / 256, 256, 0, stream>>>(cnt, csum);
  scan1_kernel<<<1, 1024, 0, stream>>>(csum, starts);
  scatter_kernel<<<CHB, 256, 0, stream>>>(esrc, edst, etyp, starts, cnt, ep);
  tile_sort_kernel<<<NTILE, 512, 0, stream>>>(ep, starts, es, ec, cofs);

  pack_w_kernel<<<(PACKED_ELEMS + 255) / 256, 256, 0, stream>>>(W, loop_w, WP);
  cvt_f16_kernel<<<(NN * DIM / 4 + 255) / 256, 256, 0, stream>>>(h0, hb0, NN * DIM / 4);

  rgcn_layer_kernel<<<NTILE, 512, 0, stream>>>(hb0, WP, bias, 0, cofs, es, ec,
                                               nullptr, hb1);
  rgcn_layer_kernel<<<NTILE, 512, 0, stream>>>(hb1, WP, bias + DIM, 1, cofs, es, ec,
                                               out, nullptr);
}

// Round 13
// 536.271 us; speedup vs baseline: 4.6672x; 4.6672x over previous
//
#include <hip/hip_runtime.h>
#include <hip/hip_bf16.h>
#include <stdint.h>

// GNN_758: stacked RelGraphConv x2.  N=50000, E=1.6M, D=128, R=20.
// agg[dst] = sum_r (sum_{e in rel r -> dst} h[src]) @ W[r]; self-loop = rel 20.
// R20: R18 base (proven 381.9us; R19's f32-LDS-atomic phase 1 regressed 10x --
// HIP atomicAdd(float) on LDS serializes; walk structure is the empirical
// optimum). Two verified micro-cuts:
//  (1) self-loop round folded: c=4 chunk deleted (2 barriers + LDS roundtrip);
//      4 MFMAs appended with A-fragment direct from global hb rows
//      (lane mapping validated by R19's passing refcheck).
//  (2) tile_sort scan: 512-wide Hillis-Steele (18 barriers) -> single-wave
//      __shfl_up scan, lane owns 5 bins (2 barriers). Same outputs.

#define NN 50000
#define NE 1600000
#define DIM 128
#define NREL 20
#define NRELP 21
#define TILE 16
#define NTILE (NN / TILE)          // 3125 = tile bins
#define CELLS (NN * NREL)          // dst*20 + r
#define CHB 256                    // chunk blocks for count/scatter
#define CHE (NE / CHB)             // 6250 edges per chunk block
#define SPK_CAP 1024               // staged srcs per block (mean 512, sd ~23)
#define PACKED_ELEMS (2 * NRELP * 4 * 8 * 64 * 8)    // 688128

typedef __attribute__((ext_vector_type(8))) short short8;
typedef __attribute__((ext_vector_type(8))) _Float16 half8;
typedef __attribute__((ext_vector_type(4))) float f32x4;

__device__ __forceinline__ unsigned short f32_to_f16_raw(float f) {
  union { _Float16 h; unsigned short u; } c;
  c.h = (_Float16)f;               // v_cvt_f16_f32 (RNE)
  return c.u;
}

// ---------------- fp32 -> f16 (x4), nontemporal stores ----------------
__global__ void cvt_f16_kernel(const float* __restrict__ in,
                               unsigned short* __restrict__ out, int n4) {
  int i = blockIdx.x * 256 + threadIdx.x;
  if (i < n4) {
    float4 f = ((const float4*)in)[i];
    unsigned long long p =
        (unsigned long long)f32_to_f16_raw(f.x)
      | ((unsigned long long)f32_to_f16_raw(f.y) << 16)
      | ((unsigned long long)f32_to_f16_raw(f.z) << 32)
      | ((unsigned long long)f32_to_f16_raw(f.w) << 48);
    __builtin_nontemporal_store(p, (unsigned long long*)out + i);  // clean -> L3
  }
}

// ---------------- pack W (+loop_w as rel 20) into B-fragment order ----------------
// WP flat: ((((l*21 + r)*4 + ks)*8 + nc)*64 + lane)*8  (verified R0/R1), f16
__global__ void pack_w_kernel(const float* __restrict__ W,
                              const float* __restrict__ loop_w,
                              unsigned short* __restrict__ WP) {
  int idx = blockIdx.x * 256 + threadIdx.x;
  if (idx >= PACKED_ELEMS) return;
  int j = idx & 7;       int t = idx >> 3;
  int lane = t & 63;     t >>= 6;
  int nc = t & 7;        t >>= 3;
  int ks = t & 3;        t >>= 2;
  int r = t % NRELP;     int l = t / NRELP;
  int k = ks * 32 + (lane >> 4) * 8 + j;
  int n = nc * 16 + (lane & 15);
  float v = (r < NREL) ? W[(((size_t)l * NREL + r) * DIM + k) * DIM + n]
                       : loop_w[((size_t)l * DIM + k) * DIM + n];
  WP[idx] = f32_to_f16_raw(v);
}

// ---------------- tile counting sort, all global accesses coalesced ----------------
// bin = dst>>4 (3125 bins).  cnt layout: [blk][NTILE] rows (coalesced).
__global__ __launch_bounds__(256) void cnt_kernel(
    const int* __restrict__ dst, unsigned int* __restrict__ cnt) {
  __shared__ unsigned int h[NTILE];              // 12.5 KB
  for (int i = threadIdx.x; i < NTILE; i += 256) h[i] = 0u;
  __syncthreads();
  const int base = blockIdx.x * CHE;
  for (int i = base + threadIdx.x; i < base + CHE; i += 256)
    atomicAdd(&h[dst[i] >> 4], 1u);              // LDS atomic
  __syncthreads();
  unsigned int* row = cnt + (size_t)blockIdx.x * NTILE;
  for (int i = threadIdx.x; i < NTILE; i += 256) row[i] = h[i];
}

// wave-per-bin exclusive prefix over the 256 chunk-blocks (in place) + totals.
__global__ __launch_bounds__(256) void colscan_kernel(
    unsigned int* __restrict__ cnt, unsigned int* __restrict__ csum) {
  const int b = (blockIdx.x * 256 + threadIdx.x) >> 6;   // bin = wave id
  const int lane = threadIdx.x & 63;
  if (b >= NTILE) return;
  unsigned int v[4], p[4], s = 0;
#pragma unroll
  for (int i = 0; i < 4; ++i) {
    v[i] = cnt[(size_t)(lane * 4 + i) * NTILE + b];
    p[i] = s; s += v[i];
  }
  unsigned int run = s;
  for (int d = 1; d < 64; d <<= 1) {
    unsigned int t = __shfl_up(run, d);
    if (lane >= d) run += t;
  }
  const unsigned int excl = run - s;     // exclusive prefix of this lane
#pragma unroll
  for (int i = 0; i < 4; ++i)
    cnt[(size_t)(lane * 4 + i) * NTILE + b] = excl + p[i];
  if (lane == 63) csum[b] = run;         // bin total
}

// single-block exclusive scan of csum[NTILE] -> starts[NTILE+1] (sentinel=NE)
__global__ __launch_bounds__(1024) void scan1_kernel(
    const unsigned int* __restrict__ csum, unsigned int* __restrict__ starts) {
  __shared__ unsigned int buf[1024];
  const int t = threadIdx.x;
  const int base = t * 4;
  unsigned int v[4], p[4], s = 0;
#pragma unroll
  for (int j = 0; j < 4; ++j) {
    v[j] = (base + j < NTILE) ? csum[base + j] : 0u;
    p[j] = s; s += v[j];
  }
  buf[t] = s;
  __syncthreads();
  for (int d = 1; d < 1024; d <<= 1) {
    unsigned int a = (t >= d) ? buf[t - d] : 0u;
    __syncthreads();
    buf[t] += a;
    __syncthreads();
  }
  unsigned int excl = buf[t] - s;
#pragma unroll
  for (int j = 0; j < 4; ++j)
    if (base + j < NTILE) starts[base + j] = excl + p[j];
  if (t == 1023) starts[NTILE] = buf[1023];      // = NE
}

// scatter to tile-sorted position. payload = src | dd<<16 | rel<<20 (5 bits).
__global__ __launch_bounds__(256) void scatter_kernel(
    const int* __restrict__ src, const int* __restrict__ dst,
    const int* __restrict__ et, const unsigned int* __restrict__ starts,
    const unsigned int* __restrict__ cnt, unsigned int* __restrict__ ep) {
  __shared__ unsigned int cur[NTILE];            // 12.5 KB
  const unsigned int* row = cnt + (size_t)blockIdx.x * NTILE;
  for (int i = threadIdx.x; i < NTILE; i += 256)
    cur[i] = starts[i] + row[i];
  __syncthreads();
  const int base = blockIdx.x * CHE;
  for (int i = base + threadIdx.x; i < base + CHE; i += 256) {
    int d = dst[i];
    unsigned int pos = atomicAdd(&cur[d >> 4], 1u);   // LDS atomic
    ep[pos] = (unsigned int)src[i] | ((unsigned int)(d & 15) << 16)
            | ((unsigned int)et[i] << 20);
  }
}

// per-tile 320-bin sort -> cofs (dst*20+r layout) + es (u16 src).
// scan = single-wave shfl (lane owns 5 bins), 2 barriers instead of 18.
__global__ __launch_bounds__(512) void tile_sort_kernel(
    const unsigned int* __restrict__ ep, const unsigned int* __restrict__ starts,
    unsigned short* __restrict__ es, unsigned int* __restrict__ cofs) {
  __shared__ unsigned int hist[320];
  const int t = threadIdx.x;
  const int tile = blockIdx.x;
  const unsigned int start = starts[tile];
  const unsigned int end = starts[tile + 1];
  const int cnt = (int)(end - start);
  if (t < 320) hist[t] = 0u;
  __syncthreads();
  for (int i = t; i < cnt; i += 512) {
    unsigned int p = ep[start + i];
    atomicAdd(&hist[((p >> 16) & 15u) * 20u + (p >> 20)], 1u);
  }
  __syncthreads();
  if (t < 64) {                          // wave 0: exclusive scan of 320 bins
    unsigned int v[5], p[5], s = 0;
#pragma unroll
    for (int j = 0; j < 5; ++j) { v[j] = hist[t * 5 + j]; p[j] = s; s += v[j]; }
    unsigned int run = s;
    for (int d = 1; d < 64; d <<= 1) {
      unsigned int x = __shfl_up(run, d);
      if (t >= d) run += x;
    }
    const unsigned int excl = run - s;
#pragma unroll
    for (int j = 0; j < 5; ++j) hist[t * 5 + j] = excl + p[j];
  }
  __syncthreads();
  if (t < 320) cofs[(size_t)tile * 320 + t] = start + hist[t];
  if (tile == NTILE - 1 && t == 0) cofs[CELLS] = (unsigned int)NE;
  __syncthreads();
  for (int i = t; i < cnt; i += 512) {
    unsigned int p = ep[start + i];
    int sub = (int)(((p >> 16) & 15u) * 20u + (p >> 20));
    unsigned int rk = atomicAdd(&hist[sub], 1u);
    es[start + rk] = (unsigned short)(p & 0xffffu);
  }
}

// ---------------- fused RGCN layer (R18 + folded self-loop) ----------------
// 3125 blocks x 512 threads (8 waves). LDS ~23.3KB -> 4 blocks/CU (wave cap).
__global__ __launch_bounds__(512, 8) void rgcn_layer_kernel(
    const unsigned short* __restrict__ hb,    // [N,128] f16
    const unsigned short* __restrict__ WP,    // packed weights, f16
    const float* __restrict__ bias,           // [128] this layer
    int layer,
    const unsigned int* __restrict__ cofs,    // [CELLS+1] cell offsets
    const unsigned short* __restrict__ es,    // [E] srcs, cell-sorted
    float* __restrict__ outf,                 // fp32 out (layer 1) or null
    unsigned short* __restrict__ outb)        // f16 out (layer 0) or null
{
  // Sb: [16 dst rows][5 rl slots * 16 slot16], slot16 = 8 f16 (16B),
  // slot index ^= (row & 15) -> conflict-free writes and reads (verified R8).
  __shared__ half8 Sb8[TILE * 80];           // 20480 B
  __shared__ unsigned int cofs_l[321];       // 1284 B
  __shared__ unsigned short spk[SPK_CAP];    // 2048 B

  const int tid  = threadIdx.x;
  const int lane = tid & 63;
  const int w    = tid >> 6;        // wave 0..7
  const int quad = lane >> 4;
  const int m    = lane & 15;
  const int mh8  = m * 8;
  const int half = w >> 2;          // 0: rl{0,1}  1: rl{2,3,4}  (wave-uniform)
  const int g    = (w & 3) * 4 + quad;   // owned dst_local 0..15
  const int dst_base = blockIdx.x * TILE;

  for (int i = tid; i < 321; i += 512) cofs_l[i] = cofs[blockIdx.x * (TILE * NREL) + i];
  __syncthreads();
  const int e0 = (int)cofs_l[0];
  const int etot = (int)cofs_l[320] - e0;
  const bool use_lds = (etot <= SPK_CAP);
  if (use_lds)
    for (int i = tid; i < etot; i += 512) spk[i] = es[e0 + i];
  __syncthreads();

  f32x4 acc = (f32x4){0.f, 0.f, 0.f, 0.f};

  for (int c = 0; c < 4; ++c) {
    // ---- phase 1: merged-range walk, packed-f16 accumulate, batch-6 ----
    {
      const int cbase = g * NREL + c * 5;
      const int rlA = half ? 2 : 0;
      const int rlB = half ? 5 : 2;
      const int beg    = (int)cofs_l[cbase + rlA] - e0;
      const int endAll = (int)cofs_l[cbase + rlB] - e0;

      half8 a = (half8)(_Float16)0;
      int rl = rlA;
      int nend = (int)cofs_l[cbase + rl + 1] - e0;

      auto flush = [&]() {
        Sb8[g * 80 + ((rl * 16 + m) ^ g)] = a;   // already f16 = MFMA format
        a = (half8)(_Float16)0;
      };
      auto bump = [&](int i) {    // advance cell state past edge index i
        while (i >= nend) {
          flush();
          ++rl;
          nend = (int)cofs_l[cbase + rl + 1] - e0;
        }
      };
      auto run_walk = [&](auto fetch) {
        for (int i = beg; i < endAll; i += 6) {
          const int nrem = endAll - i;
          half8 h0, h1, h2, h3, h4, h5;
          h0 = fetch(i);
          if (nrem > 1) h1 = fetch(i + 1);
          if (nrem > 2) h2 = fetch(i + 2);
          if (nrem > 3) h3 = fetch(i + 3);
          if (nrem > 4) h4 = fetch(i + 4);
          if (nrem > 5) h5 = fetch(i + 5);
          bump(i);      a += h0;          // 4x v_pk_add_f16
          if (nrem > 1) { bump(i + 1); a += h1; }
          if (nrem > 2) { bump(i + 2); a += h2; }
          if (nrem > 3) { bump(i + 3); a += h3; }
          if (nrem > 4) { bump(i + 4); a += h4; }
          if (nrem > 5) { bump(i + 5); a += h5; }
        }
        while (rl < rlB) { flush(); ++rl; }   // trailing (incl. empty) cells
      };

      if (use_lds) {
        run_walk([&](int i) {
          return *(const half8*)(hb + (size_t)spk[i] * DIM + mh8);
        });
      } else {   // overflow fallback (essentially never taken)
        run_walk([&](int i) {
          return *(const half8*)(hb + (size_t)es[e0 + i] * DIM + mh8);
        });
      }
    }
    __syncthreads();

    // ---- phase 2: nc-split 8 ways. wave w owns cols [16w,16w+16) ----
    for (int rl2 = 0; rl2 < 5; ++rl2) {
      const int r = c * 5 + rl2;
      const unsigned short* bp =
          WP + ((((size_t)(layer * NRELP + r) * 4) * 8 + w) * 64 + lane) * 8;
#pragma unroll
      for (int ks = 0; ks < 4; ++ks) {
        half8 av = Sb8[m * 80 + ((rl2 * 16 + ks * 4 + quad) ^ m)];
        half8 bv = *(const half8*)(bp + (size_t)ks * 4096);
        acc = __builtin_amdgcn_mfma_f32_16x16x32_f16(av, bv, acc, 0, 0, 0);
      }
    }
    __syncthreads();
  }

  // ---- self-loop (rel 20): A-fragment direct from global own rows ----
  // (lane mapping validated by R19's passing refcheck)
  {
    const unsigned short* bp =
        WP + ((((size_t)(layer * NRELP + NREL) * 4) * 8 + w) * 64 + lane) * 8;
#pragma unroll
    for (int ks = 0; ks < 4; ++ks) {
      half8 av = *(const half8*)(hb + (size_t)(dst_base + m) * DIM + (ks * 4 + quad) * 8);
      half8 bv = *(const half8*)(bp + (size_t)ks * 4096);
      acc = __builtin_amdgcn_mfma_f32_16x16x32_f16(av, bv, acc, 0, 0, 0);
    }
  }

  // ---- epilogue: wave w stores its 16-col tile; no cross-wave reduction ----
  const int col = w * 16 + m;
  const float bv = bias[col];
  if (outb) {
#pragma unroll
    for (int i = 0; i < 4; ++i)
      outb[(size_t)(dst_base + quad * 4 + i) * DIM + col] =
          f32_to_f16_raw(acc[i] + bv);
  } else {
#pragma unroll
    for (int i = 0; i < 4; ++i)
      outf[(size_t)(dst_base + quad * 4 + i) * DIM + col] = acc[i] + bv;
  }
}

// ---------------- launch ----------------
extern "C" void kernel_launch(void* const* d_in, const int* in_sizes, int n_in,
                              void* d_out, int out_size, void* d_ws, size_t ws_size,
                              hipStream_t stream) {
  const float* h0     = (const float*)d_in[0];
  const float* W      = (const float*)d_in[1];
  const float* loop_w = (const float*)d_in[2];
  const float* bias   = (const float*)d_in[3];
  const int* esrc     = (const int*)d_in[4];
  const int* edst     = (const int*)d_in[5];
  const int* etyp     = (const int*)d_in[6];
  float* out = (float*)d_out;

  char* ws = (char*)d_ws;
  size_t off = 0;
  auto alloc = [&](size_t bytes) -> void* {
    void* p = ws + off;
    off = (off + bytes + 255) & ~(size_t)255;
    return p;
  };
  unsigned short* hb0   = (unsigned short*)alloc((size_t)NN * DIM * 2);   // 12.8 MB
  unsigned short* hb1   = (unsigned short*)alloc((size_t)NN * DIM * 2);   // 12.8 MB
  unsigned short* WP    = (unsigned short*)alloc((size_t)PACKED_ELEMS * 2);
  unsigned int*   cnt   = (unsigned int*)alloc((size_t)CHB * NTILE * 4);  // 3.2 MB
  unsigned int*   csum  = (unsigned int*)alloc((size_t)NTILE * 4);
  unsigned int*   starts= (unsigned int*)alloc((size_t)(NTILE + 1) * 4);
  unsigned int*   ep    = (unsigned int*)alloc((size_t)NE * 4);           // 6.4 MB
  unsigned int*   cofs  = (unsigned int*)alloc((size_t)(CELLS + 1) * 4);  // 4 MB
  unsigned short* es    = (unsigned short*)alloc((size_t)NE * 2);         // 3.2 MB

  cnt_kernel<<<CHB, 256, 0, stream>>>(edst, cnt);
  colscan_kernel<<<(NTILE * 64 + 255) / 256, 256, 0, stream>>>(cnt, csum);
  scan1_kernel<<<1, 1024, 0, stream>>>(csum, starts);
  scatter_kernel<<<CHB, 256, 0, stream>>>(esrc, edst, etyp, starts, cnt, ep);
  tile_sort_kernel<<<NTILE, 512, 0, stream>>>(ep, starts, es, cofs);

  pack_w_kernel<<<(PACKED_ELEMS + 255) / 256, 256, 0, stream>>>(W, loop_w, WP);
  cvt_f16_kernel<<<(NN * DIM / 4 + 255) / 256, 256, 0, stream>>>(h0, hb0, NN * DIM / 4);

  rgcn_layer_kernel<<<NTILE, 512, 0, stream>>>(hb0, WP, bias, 0, cofs, es,
                                               nullptr, hb1);
  rgcn_layer_kernel<<<NTILE, 512, 0, stream>>>(hb1, WP, bias + DIM, 1, cofs, es,
                                               out, nullptr);
}

// Round 14
// 398.020 us; speedup vs baseline: 6.2884x; 1.3473x over previous
//
#include <hip/hip_runtime.h>
#include <hip/hip_bf16.h>
#include <stdint.h>

// GNN_758: stacked RelGraphConv x2.  N=50000, E=1.6M, D=128, R=20.
// agg[dst] = sum_r (sum_{e in rel r -> dst} h[src]) @ W[r]; self-loop = rel 20.
// R21: revert layer to R18 exact (proven 124us). R20's folded self-loop
// spilled: its 8 loop-invariant global loads got LICM-hoisted to kernel
// entry, +32 VGPRs live across the walk -> over the 64 cap (WRITE_SIZE
// 12.5->162MB, 21ms first-touch scratch alloc). Keep R20's tile_sort
// single-wave __shfl_up scan (correct, 2 barriers vs 18).
// Layer: 512thr/8waves, batch-6 f16 walk + XOR-swizzled Sb + f16 MFMA,
// LDS self-loop chunk c=4. Prep: cnt/colscan/scan1/scatter/tile_sort.

#define NN 50000
#define NE 1600000
#define DIM 128
#define NREL 20
#define NRELP 21
#define TILE 16
#define NTILE (NN / TILE)          // 3125 = tile bins
#define CELLS (NN * NREL)          // dst*20 + r
#define CHB 256                    // chunk blocks for count/scatter
#define CHE (NE / CHB)             // 6250 edges per chunk block
#define SPK_CAP 1024               // staged srcs per block (mean 512, sd ~23)
#define PACKED_ELEMS (2 * NRELP * 4 * 8 * 64 * 8)    // 688128

typedef __attribute__((ext_vector_type(8))) short short8;
typedef __attribute__((ext_vector_type(8))) _Float16 half8;
typedef __attribute__((ext_vector_type(4))) float f32x4;

__device__ __forceinline__ unsigned short f32_to_f16_raw(float f) {
  union { _Float16 h; unsigned short u; } c;
  c.h = (_Float16)f;               // v_cvt_f16_f32 (RNE)
  return c.u;
}

// ---------------- fp32 -> f16 (x4), nontemporal stores ----------------
__global__ void cvt_f16_kernel(const float* __restrict__ in,
                               unsigned short* __restrict__ out, int n4) {
  int i = blockIdx.x * 256 + threadIdx.x;
  if (i < n4) {
    float4 f = ((const float4*)in)[i];
    unsigned long long p =
        (unsigned long long)f32_to_f16_raw(f.x)
      | ((unsigned long long)f32_to_f16_raw(f.y) << 16)
      | ((unsigned long long)f32_to_f16_raw(f.z) << 32)
      | ((unsigned long long)f32_to_f16_raw(f.w) << 48);
    __builtin_nontemporal_store(p, (unsigned long long*)out + i);  // clean -> L3
  }
}

// ---------------- pack W (+loop_w as rel 20) into B-fragment order ----------------
// WP flat: ((((l*21 + r)*4 + ks)*8 + nc)*64 + lane)*8  (verified R0/R1), f16
__global__ void pack_w_kernel(const float* __restrict__ W,
                              const float* __restrict__ loop_w,
                              unsigned short* __restrict__ WP) {
  int idx = blockIdx.x * 256 + threadIdx.x;
  if (idx >= PACKED_ELEMS) return;
  int j = idx & 7;       int t = idx >> 3;
  int lane = t & 63;     t >>= 6;
  int nc = t & 7;        t >>= 3;
  int ks = t & 3;        t >>= 2;
  int r = t % NRELP;     int l = t / NRELP;
  int k = ks * 32 + (lane >> 4) * 8 + j;
  int n = nc * 16 + (lane & 15);
  float v = (r < NREL) ? W[(((size_t)l * NREL + r) * DIM + k) * DIM + n]
                       : loop_w[((size_t)l * DIM + k) * DIM + n];
  WP[idx] = f32_to_f16_raw(v);
}

// ---------------- tile counting sort, all global accesses coalesced ----------------
// bin = dst>>4 (3125 bins).  cnt layout: [blk][NTILE] rows (coalesced).
__global__ __launch_bounds__(256) void cnt_kernel(
    const int* __restrict__ dst, unsigned int* __restrict__ cnt) {
  __shared__ unsigned int h[NTILE];              // 12.5 KB
  for (int i = threadIdx.x; i < NTILE; i += 256) h[i] = 0u;
  __syncthreads();
  const int base = blockIdx.x * CHE;
  for (int i = base + threadIdx.x; i < base + CHE; i += 256)
    atomicAdd(&h[dst[i] >> 4], 1u);              // LDS atomic
  __syncthreads();
  unsigned int* row = cnt + (size_t)blockIdx.x * NTILE;
  for (int i = threadIdx.x; i < NTILE; i += 256) row[i] = h[i];
}

// wave-per-bin exclusive prefix over the 256 chunk-blocks (in place) + totals.
__global__ __launch_bounds__(256) void colscan_kernel(
    unsigned int* __restrict__ cnt, unsigned int* __restrict__ csum) {
  const int b = (blockIdx.x * 256 + threadIdx.x) >> 6;   // bin = wave id
  const int lane = threadIdx.x & 63;
  if (b >= NTILE) return;
  unsigned int v[4], p[4], s = 0;
#pragma unroll
  for (int i = 0; i < 4; ++i) {
    v[i] = cnt[(size_t)(lane * 4 + i) * NTILE + b];
    p[i] = s; s += v[i];
  }
  unsigned int run = s;
  for (int d = 1; d < 64; d <<= 1) {
    unsigned int t = __shfl_up(run, d);
    if (lane >= d) run += t;
  }
  const unsigned int excl = run - s;     // exclusive prefix of this lane
#pragma unroll
  for (int i = 0; i < 4; ++i)
    cnt[(size_t)(lane * 4 + i) * NTILE + b] = excl + p[i];
  if (lane == 63) csum[b] = run;         // bin total
}

// single-block exclusive scan of csum[NTILE] -> starts[NTILE+1] (sentinel=NE)
__global__ __launch_bounds__(1024) void scan1_kernel(
    const unsigned int* __restrict__ csum, unsigned int* __restrict__ starts) {
  __shared__ unsigned int buf[1024];
  const int t = threadIdx.x;
  const int base = t * 4;
  unsigned int v[4], p[4], s = 0;
#pragma unroll
  for (int j = 0; j < 4; ++j) {
    v[j] = (base + j < NTILE) ? csum[base + j] : 0u;
    p[j] = s; s += v[j];
  }
  buf[t] = s;
  __syncthreads();
  for (int d = 1; d < 1024; d <<= 1) {
    unsigned int a = (t >= d) ? buf[t - d] : 0u;
    __syncthreads();
    buf[t] += a;
    __syncthreads();
  }
  unsigned int excl = buf[t] - s;
#pragma unroll
  for (int j = 0; j < 4; ++j)
    if (base + j < NTILE) starts[base + j] = excl + p[j];
  if (t == 1023) starts[NTILE] = buf[1023];      // = NE
}

// scatter to tile-sorted position. payload = src | dd<<16 | rel<<20 (5 bits).
__global__ __launch_bounds__(256) void scatter_kernel(
    const int* __restrict__ src, const int* __restrict__ dst,
    const int* __restrict__ et, const unsigned int* __restrict__ starts,
    const unsigned int* __restrict__ cnt, unsigned int* __restrict__ ep) {
  __shared__ unsigned int cur[NTILE];            // 12.5 KB
  const unsigned int* row = cnt + (size_t)blockIdx.x * NTILE;
  for (int i = threadIdx.x; i < NTILE; i += 256)
    cur[i] = starts[i] + row[i];
  __syncthreads();
  const int base = blockIdx.x * CHE;
  for (int i = base + threadIdx.x; i < base + CHE; i += 256) {
    int d = dst[i];
    unsigned int pos = atomicAdd(&cur[d >> 4], 1u);   // LDS atomic
    ep[pos] = (unsigned int)src[i] | ((unsigned int)(d & 15) << 16)
            | ((unsigned int)et[i] << 20);
  }
}

// per-tile 320-bin sort -> cofs (dst*20+r layout) + es (u16 src).
// scan = single-wave shfl (lane owns 5 bins), 2 barriers instead of 18.
__global__ __launch_bounds__(512) void tile_sort_kernel(
    const unsigned int* __restrict__ ep, const unsigned int* __restrict__ starts,
    unsigned short* __restrict__ es, unsigned int* __restrict__ cofs) {
  __shared__ unsigned int hist[320];
  const int t = threadIdx.x;
  const int tile = blockIdx.x;
  const unsigned int start = starts[tile];
  const unsigned int end = starts[tile + 1];
  const int cnt = (int)(end - start);
  if (t < 320) hist[t] = 0u;
  __syncthreads();
  for (int i = t; i < cnt; i += 512) {
    unsigned int p = ep[start + i];
    atomicAdd(&hist[((p >> 16) & 15u) * 20u + (p >> 20)], 1u);
  }
  __syncthreads();
  if (t < 64) {                          // wave 0: exclusive scan of 320 bins
    unsigned int v[5], p[5], s = 0;
#pragma unroll
    for (int j = 0; j < 5; ++j) { v[j] = hist[t * 5 + j]; p[j] = s; s += v[j]; }
    unsigned int run = s;
    for (int d = 1; d < 64; d <<= 1) {
      unsigned int x = __shfl_up(run, d);
      if (t >= d) run += x;
    }
    const unsigned int excl = run - s;
#pragma unroll
    for (int j = 0; j < 5; ++j) hist[t * 5 + j] = excl + p[j];
  }
  __syncthreads();
  if (t < 320) cofs[(size_t)tile * 320 + t] = start + hist[t];
  if (tile == NTILE - 1 && t == 0) cofs[CELLS] = (unsigned int)NE;
  __syncthreads();
  for (int i = t; i < cnt; i += 512) {
    unsigned int p = ep[start + i];
    int sub = (int)(((p >> 16) & 15u) * 20u + (p >> 20));
    unsigned int rk = atomicAdd(&hist[sub], 1u);
    es[start + rk] = (unsigned short)(p & 0xffffu);
  }
}

// ---------------- fused RGCN layer (R18 verbatim) ----------------
// 3125 blocks x 512 threads (8 waves). LDS ~23.3KB -> 4 blocks/CU (wave cap).
__global__ __launch_bounds__(512, 8) void rgcn_layer_kernel(
    const unsigned short* __restrict__ hb,    // [N,128] f16
    const unsigned short* __restrict__ WP,    // packed weights, f16
    const float* __restrict__ bias,           // [128] this layer
    int layer,
    const unsigned int* __restrict__ cofs,    // [CELLS+1] cell offsets
    const unsigned short* __restrict__ es,    // [E] srcs, cell-sorted
    float* __restrict__ outf,                 // fp32 out (layer 1) or null
    unsigned short* __restrict__ outb)        // f16 out (layer 0) or null
{
  // Sb: [16 dst rows][5 rl slots * 16 slot16], slot16 = 8 f16 (16B),
  // slot index ^= (row & 15) -> conflict-free writes and reads (verified R8).
  __shared__ half8 Sb8[TILE * 80];           // 20480 B
  __shared__ unsigned int cofs_l[321];       // 1284 B
  __shared__ unsigned short spk[SPK_CAP];    // 2048 B

  const int tid  = threadIdx.x;
  const int lane = tid & 63;
  const int w    = tid >> 6;        // wave 0..7
  const int quad = lane >> 4;
  const int m    = lane & 15;
  const int mh8  = m * 8;
  const int half = w >> 2;          // 0: rl{0,1}  1: rl{2,3,4}  (wave-uniform)
  const int g    = (w & 3) * 4 + quad;   // owned dst_local 0..15
  const int dst_base = blockIdx.x * TILE;

  for (int i = tid; i < 321; i += 512) cofs_l[i] = cofs[blockIdx.x * (TILE * NREL) + i];
  __syncthreads();
  const int e0 = (int)cofs_l[0];
  const int etot = (int)cofs_l[320] - e0;
  const bool use_lds = (etot <= SPK_CAP);
  if (use_lds)
    for (int i = tid; i < etot; i += 512) spk[i] = es[e0 + i];
  __syncthreads();

  f32x4 acc = (f32x4){0.f, 0.f, 0.f, 0.f};

  for (int c = 0; c < 5; ++c) {
    // ---- phase 1: merged-range walk, packed-f16 accumulate, batch-6 ----
    if (c < 4) {
      const int cbase = g * NREL + c * 5;
      const int rlA = half ? 2 : 0;
      const int rlB = half ? 5 : 2;
      const int beg    = (int)cofs_l[cbase + rlA] - e0;
      const int endAll = (int)cofs_l[cbase + rlB] - e0;

      half8 a = (half8)(_Float16)0;
      int rl = rlA;
      int nend = (int)cofs_l[cbase + rl + 1] - e0;

      auto flush = [&]() {
        Sb8[g * 80 + ((rl * 16 + m) ^ g)] = a;   // already f16 = MFMA format
        a = (half8)(_Float16)0;
      };
      auto bump = [&](int i) {    // advance cell state past edge index i
        while (i >= nend) {
          flush();
          ++rl;
          nend = (int)cofs_l[cbase + rl + 1] - e0;
        }
      };
      auto run_walk = [&](auto fetch) {
        for (int i = beg; i < endAll; i += 6) {
          const int nrem = endAll - i;
          half8 h0, h1, h2, h3, h4, h5;
          h0 = fetch(i);
          if (nrem > 1) h1 = fetch(i + 1);
          if (nrem > 2) h2 = fetch(i + 2);
          if (nrem > 3) h3 = fetch(i + 3);
          if (nrem > 4) h4 = fetch(i + 4);
          if (nrem > 5) h5 = fetch(i + 5);
          bump(i);      a += h0;          // 4x v_pk_add_f16
          if (nrem > 1) { bump(i + 1); a += h1; }
          if (nrem > 2) { bump(i + 2); a += h2; }
          if (nrem > 3) { bump(i + 3); a += h3; }
          if (nrem > 4) { bump(i + 4); a += h4; }
          if (nrem > 5) { bump(i + 5); a += h5; }
        }
        while (rl < rlB) { flush(); ++rl; }   // trailing (incl. empty) cells
      };

      if (use_lds) {
        run_walk([&](int i) {
          return *(const half8*)(hb + (size_t)spk[i] * DIM + mh8);
        });
      } else {   // overflow fallback (essentially never taken)
        run_walk([&](int i) {
          return *(const half8*)(hb + (size_t)es[e0 + i] * DIM + mh8);
        });
      }
    } else if (half == 0) {
      // self-loop mini-chunk: own row (feeds rel 20 = loop_w), slot 0
      half8 hv = *(const half8*)(hb + (size_t)(dst_base + g) * DIM + mh8);
      Sb8[g * 80 + (m ^ g)] = hv;   // already f16; sum of one row
    }
    __syncthreads();

    // ---- phase 2: nc-split 8 ways. wave w owns cols [16w,16w+16) ----
    const int rc = (c == 4) ? 1 : 5;
    for (int rl2 = 0; rl2 < rc; ++rl2) {
      const int r = (c == 4) ? (NRELP - 1) : (c * 5 + rl2);
      const unsigned short* bp =
          WP + ((((size_t)(layer * NRELP + r) * 4) * 8 + w) * 64 + lane) * 8;
#pragma unroll
      for (int ks = 0; ks < 4; ++ks) {
        half8 av = Sb8[m * 80 + ((rl2 * 16 + ks * 4 + quad) ^ m)];
        half8 bv = *(const half8*)(bp + (size_t)ks * 4096);
        acc = __builtin_amdgcn_mfma_f32_16x16x32_f16(av, bv, acc, 0, 0, 0);
      }
    }
    __syncthreads();
  }

  // ---- epilogue: wave w stores its 16-col tile; no cross-wave reduction ----
  const int col = w * 16 + m;
  const float bv = bias[col];
  if (outb) {
#pragma unroll
    for (int i = 0; i < 4; ++i)
      outb[(size_t)(dst_base + quad * 4 + i) * DIM + col] =
          f32_to_f16_raw(acc[i] + bv);
  } else {
#pragma unroll
    for (int i = 0; i < 4; ++i)
      outf[(size_t)(dst_base + quad * 4 + i) * DIM + col] = acc[i] + bv;
  }
}

// ---------------- launch ----------------
extern "C" void kernel_launch(void* const* d_in, const int* in_sizes, int n_in,
                              void* d_out, int out_size, void* d_ws, size_t ws_size,
                              hipStream_t stream) {
  const float* h0     = (const float*)d_in[0];
  const float* W      = (const float*)d_in[1];
  const float* loop_w = (const float*)d_in[2];
  const float* bias   = (const float*)d_in[3];
  const int* esrc     = (const int*)d_in[4];
  const int* edst     = (const int*)d_in[5];
  const int* etyp     = (const int*)d_in[6];
  float* out = (float*)d_out;

  char* ws = (char*)d_ws;
  size_t off = 0;
  auto alloc = [&](size_t bytes) -> void* {
    void* p = ws + off;
    off = (off + bytes + 255) & ~(size_t)255;
    return p;
  };
  unsigned short* hb0   = (unsigned short*)alloc((size_t)NN * DIM * 2);   // 12.8 MB
  unsigned short* hb1   = (unsigned short*)alloc((size_t)NN * DIM * 2);   // 12.8 MB
  unsigned short* WP    = (unsigned short*)alloc((size_t)PACKED_ELEMS * 2);
  unsigned int*   cnt   = (unsigned int*)alloc((size_t)CHB * NTILE * 4);  // 3.2 MB
  unsigned int*   csum  = (unsigned int*)alloc((size_t)NTILE * 4);
  unsigned int*   starts= (unsigned int*)alloc((size_t)(NTILE + 1) * 4);
  unsigned int*   ep    = (unsigned int*)alloc((size_t)NE * 4);           // 6.4 MB
  unsigned int*   cofs  = (unsigned int*)alloc((size_t)(CELLS + 1) * 4);  // 4 MB
  unsigned short* es    = (unsigned short*)alloc((size_t)NE * 2);         // 3.2 MB

  cnt_kernel<<<CHB, 256, 0, stream>>>(edst, cnt);
  colscan_kernel<<<(NTILE * 64 + 255) / 256, 256, 0, stream>>>(cnt, csum);
  scan1_kernel<<<1, 1024, 0, stream>>>(csum, starts);
  scatter_kernel<<<CHB, 256, 0, stream>>>(esrc, edst, etyp, starts, cnt, ep);
  tile_sort_kernel<<<NTILE, 512, 0, stream>>>(ep, starts, es, cofs);

  pack_w_kernel<<<(PACKED_ELEMS + 255) / 256, 256, 0, stream>>>(W, loop_w, WP);
  cvt_f16_kernel<<<(NN * DIM / 4 + 255) / 256, 256, 0, stream>>>(h0, hb0, NN * DIM / 4);

  rgcn_layer_kernel<<<NTILE, 512, 0, stream>>>(hb0, WP, bias, 0, cofs, es,
                                               nullptr, hb1);
  rgcn_layer_kernel<<<NTILE, 512, 0, stream>>>(hb1, WP, bias + DIM, 1, cofs, es,
                                               out, nullptr);
}

// Round 15
// 395.125 us; speedup vs baseline: 6.3345x; 1.0073x over previous
//
#include <hip/hip_runtime.h>
#include <hip/hip_bf16.h>
#include <stdint.h>

// GNN_758: stacked RelGraphConv x2.  N=50000, E=1.6M, D=128, R=20.
// agg[dst] = sum_r (sum_{e in rel r -> dst} h[src]) @ W[r]; self-loop = rel 20.
// R22: layer = R18/R21 exact (proven 123us floor; frozen after 10 structural
// attempts). Prep changes only:
//  (1) tile_sort reverted to R18's 512-thread Hillis-Steele scan (R21's
//      single-wave scan coincided with +16us prep; restore the proven one).
//  (2) entry fusion: cnt + cvt_f16 + pack_w are independent -> ONE dispatch
//      branching on blockIdx (256 cnt + 6250 cvt + 2688 pack blocks).
//      Saves 2 launch boundaries; overlaps cnt's LDS-atomic latency with
//      cvt's streaming BW.

#define NN 50000
#define NE 1600000
#define DIM 128
#define NREL 20
#define NRELP 21
#define TILE 16
#define NTILE (NN / TILE)          // 3125 = tile bins
#define CELLS (NN * NREL)          // dst*20 + r
#define CHB 256                    // chunk blocks for count/scatter
#define CHE (NE / CHB)             // 6250 edges per chunk block
#define SPK_CAP 1024               // staged srcs per block (mean 512, sd ~23)
#define PACKED_ELEMS (2 * NRELP * 4 * 8 * 64 * 8)    // 688128
#define CVT_BLKS (NN * DIM / 4 / 256)                // 6250 (exact)
#define PKW_BLKS ((PACKED_ELEMS + 255) / 256)        // 2688

typedef __attribute__((ext_vector_type(8))) short short8;
typedef __attribute__((ext_vector_type(8))) _Float16 half8;
typedef __attribute__((ext_vector_type(4))) float f32x4;

__device__ __forceinline__ unsigned short f32_to_f16_raw(float f) {
  union { _Float16 h; unsigned short u; } c;
  c.h = (_Float16)f;               // v_cvt_f16_f32 (RNE)
  return c.u;
}

// ---------------- fused entry: cnt | cvt_f16 | pack_w ----------------
// blocks [0,CHB): tile hist.  [CHB,CHB+CVT_BLKS): h0->f16.  rest: pack W.
__global__ __launch_bounds__(256) void entry_kernel(
    const int* __restrict__ dst, unsigned int* __restrict__ cnt,
    const float* __restrict__ h0, unsigned short* __restrict__ hb0,
    const float* __restrict__ W, const float* __restrict__ loop_w,
    unsigned short* __restrict__ WP) {
  const int b = blockIdx.x;
  if (b < CHB) {
    // -- tile counting: bin = dst>>4, LDS-privatized, coalesced row write --
    __shared__ unsigned int h[NTILE];            // 12.5 KB
    for (int i = threadIdx.x; i < NTILE; i += 256) h[i] = 0u;
    __syncthreads();
    const int base = b * CHE;
    for (int i = base + threadIdx.x; i < base + CHE; i += 256)
      atomicAdd(&h[dst[i] >> 4], 1u);            // LDS atomic
    __syncthreads();
    unsigned int* row = cnt + (size_t)b * NTILE;
    for (int i = threadIdx.x; i < NTILE; i += 256) row[i] = h[i];
  } else if (b < CHB + CVT_BLKS) {
    // -- fp32 -> f16 (x4), nontemporal stores --
    const int i = (b - CHB) * 256 + threadIdx.x;   // < NN*DIM/4 exactly
    float4 f = ((const float4*)h0)[i];
    unsigned long long p =
        (unsigned long long)f32_to_f16_raw(f.x)
      | ((unsigned long long)f32_to_f16_raw(f.y) << 16)
      | ((unsigned long long)f32_to_f16_raw(f.z) << 32)
      | ((unsigned long long)f32_to_f16_raw(f.w) << 48);
    __builtin_nontemporal_store(p, (unsigned long long*)hb0 + i);
  } else {
    // -- pack W (+loop_w as rel 20) into B-fragment order, f16 --
    // WP flat: ((((l*21 + r)*4 + ks)*8 + nc)*64 + lane)*8  (verified R0/R1)
    const int idx = (b - CHB - CVT_BLKS) * 256 + threadIdx.x;
    if (idx >= PACKED_ELEMS) return;
    int j = idx & 7;       int t = idx >> 3;
    int lane = t & 63;     t >>= 6;
    int nc = t & 7;        t >>= 3;
    int ks = t & 3;        t >>= 2;
    int r = t % NRELP;     int l = t / NRELP;
    int k = ks * 32 + (lane >> 4) * 8 + j;
    int n = nc * 16 + (lane & 15);
    float v = (r < NREL) ? W[(((size_t)l * NREL + r) * DIM + k) * DIM + n]
                         : loop_w[((size_t)l * DIM + k) * DIM + n];
    WP[idx] = f32_to_f16_raw(v);
  }
}

// wave-per-bin exclusive prefix over the 256 chunk-blocks (in place) + totals.
__global__ __launch_bounds__(256) void colscan_kernel(
    unsigned int* __restrict__ cnt, unsigned int* __restrict__ csum) {
  const int b = (blockIdx.x * 256 + threadIdx.x) >> 6;   // bin = wave id
  const int lane = threadIdx.x & 63;
  if (b >= NTILE) return;
  unsigned int v[4], p[4], s = 0;
#pragma unroll
  for (int i = 0; i < 4; ++i) {
    v[i] = cnt[(size_t)(lane * 4 + i) * NTILE + b];
    p[i] = s; s += v[i];
  }
  unsigned int run = s;
  for (int d = 1; d < 64; d <<= 1) {
    unsigned int t = __shfl_up(run, d);
    if (lane >= d) run += t;
  }
  const unsigned int excl = run - s;     // exclusive prefix of this lane
#pragma unroll
  for (int i = 0; i < 4; ++i)
    cnt[(size_t)(lane * 4 + i) * NTILE + b] = excl + p[i];
  if (lane == 63) csum[b] = run;         // bin total
}

// single-block exclusive scan of csum[NTILE] -> starts[NTILE+1] (sentinel=NE)
__global__ __launch_bounds__(1024) void scan1_kernel(
    const unsigned int* __restrict__ csum, unsigned int* __restrict__ starts) {
  __shared__ unsigned int buf[1024];
  const int t = threadIdx.x;
  const int base = t * 4;
  unsigned int v[4], p[4], s = 0;
#pragma unroll
  for (int j = 0; j < 4; ++j) {
    v[j] = (base + j < NTILE) ? csum[base + j] : 0u;
    p[j] = s; s += v[j];
  }
  buf[t] = s;
  __syncthreads();
  for (int d = 1; d < 1024; d <<= 1) {
    unsigned int a = (t >= d) ? buf[t - d] : 0u;
    __syncthreads();
    buf[t] += a;
    __syncthreads();
  }
  unsigned int excl = buf[t] - s;
#pragma unroll
  for (int j = 0; j < 4; ++j)
    if (base + j < NTILE) starts[base + j] = excl + p[j];
  if (t == 1023) starts[NTILE] = buf[1023];      // = NE
}

// scatter to tile-sorted position. payload = src | dd<<16 | rel<<20 (5 bits).
__global__ __launch_bounds__(256) void scatter_kernel(
    const int* __restrict__ src, const int* __restrict__ dst,
    const int* __restrict__ et, const unsigned int* __restrict__ starts,
    const unsigned int* __restrict__ cnt, unsigned int* __restrict__ ep) {
  __shared__ unsigned int cur[NTILE];            // 12.5 KB
  const unsigned int* row = cnt + (size_t)blockIdx.x * NTILE;
  for (int i = threadIdx.x; i < NTILE; i += 256)
    cur[i] = starts[i] + row[i];
  __syncthreads();
  const int base = blockIdx.x * CHE;
  for (int i = base + threadIdx.x; i < base + CHE; i += 256) {
    int d = dst[i];
    unsigned int pos = atomicAdd(&cur[d >> 4], 1u);   // LDS atomic
    ep[pos] = (unsigned int)src[i] | ((unsigned int)(d & 15) << 16)
            | ((unsigned int)et[i] << 20);
  }
}

// per-tile 320-bin sort -> cofs (dst*20+r layout) + es (u16 src).
// (R18-proven version: 512-thread Hillis-Steele scan.)
__global__ __launch_bounds__(512) void tile_sort_kernel(
    const unsigned int* __restrict__ ep, const unsigned int* __restrict__ starts,
    unsigned short* __restrict__ es, unsigned int* __restrict__ cofs) {
  __shared__ unsigned int hist[512];             // 320 bins, padded for scan
  const int t = threadIdx.x;
  const int tile = blockIdx.x;
  const unsigned int start = starts[tile];
  const unsigned int end = starts[tile + 1];
  const int cnt = (int)(end - start);
  hist[t] = 0u;
  __syncthreads();
  for (int i = t; i < cnt; i += 512) {
    unsigned int p = ep[start + i];
    atomicAdd(&hist[((p >> 16) & 15u) * 20u + (p >> 20)], 1u);
  }
  __syncthreads();
  unsigned int own = hist[t];
  for (int d = 1; d < 512; d <<= 1) {
    __syncthreads();
    unsigned int a = (t >= d) ? hist[t - d] : 0u;
    __syncthreads();
    hist[t] += a;
  }
  __syncthreads();
  unsigned int excl = hist[t] - own;     // exclusive prefix (own slot only)
  hist[t] = excl;                        // becomes rank cursor
  if (t < 320) cofs[(size_t)tile * 320 + t] = start + excl;
  if (tile == NTILE - 1 && t == 0) cofs[CELLS] = (unsigned int)NE;
  __syncthreads();
  for (int i = t; i < cnt; i += 512) {
    unsigned int p = ep[start + i];
    int sub = (int)(((p >> 16) & 15u) * 20u + (p >> 20));
    unsigned int rk = atomicAdd(&hist[sub], 1u);
    es[start + rk] = (unsigned short)(p & 0xffffu);
  }
}

// ---------------- fused RGCN layer (R18 verbatim, frozen) ----------------
// 3125 blocks x 512 threads (8 waves). LDS ~23.3KB -> 4 blocks/CU (wave cap).
__global__ __launch_bounds__(512, 8) void rgcn_layer_kernel(
    const unsigned short* __restrict__ hb,    // [N,128] f16
    const unsigned short* __restrict__ WP,    // packed weights, f16
    const float* __restrict__ bias,           // [128] this layer
    int layer,
    const unsigned int* __restrict__ cofs,    // [CELLS+1] cell offsets
    const unsigned short* __restrict__ es,    // [E] srcs, cell-sorted
    float* __restrict__ outf,                 // fp32 out (layer 1) or null
    unsigned short* __restrict__ outb)        // f16 out (layer 0) or null
{
  // Sb: [16 dst rows][5 rl slots * 16 slot16], slot16 = 8 f16 (16B),
  // slot index ^= (row & 15) -> conflict-free writes and reads (verified R8).
  __shared__ half8 Sb8[TILE * 80];           // 20480 B
  __shared__ unsigned int cofs_l[321];       // 1284 B
  __shared__ unsigned short spk[SPK_CAP];    // 2048 B

  const int tid  = threadIdx.x;
  const int lane = tid & 63;
  const int w    = tid >> 6;        // wave 0..7
  const int quad = lane >> 4;
  const int m    = lane & 15;
  const int mh8  = m * 8;
  const int half = w >> 2;          // 0: rl{0,1}  1: rl{2,3,4}  (wave-uniform)
  const int g    = (w & 3) * 4 + quad;   // owned dst_local 0..15
  const int dst_base = blockIdx.x * TILE;

  for (int i = tid; i < 321; i += 512) cofs_l[i] = cofs[blockIdx.x * (TILE * NREL) + i];
  __syncthreads();
  const int e0 = (int)cofs_l[0];
  const int etot = (int)cofs_l[320] - e0;
  const bool use_lds = (etot <= SPK_CAP);
  if (use_lds)
    for (int i = tid; i < etot; i += 512) spk[i] = es[e0 + i];
  __syncthreads();

  f32x4 acc = (f32x4){0.f, 0.f, 0.f, 0.f};

  for (int c = 0; c < 5; ++c) {
    // ---- phase 1: merged-range walk, packed-f16 accumulate, batch-6 ----
    if (c < 4) {
      const int cbase = g * NREL + c * 5;
      const int rlA = half ? 2 : 0;
      const int rlB = half ? 5 : 2;
      const int beg    = (int)cofs_l[cbase + rlA] - e0;
      const int endAll = (int)cofs_l[cbase + rlB] - e0;

      half8 a = (half8)(_Float16)0;
      int rl = rlA;
      int nend = (int)cofs_l[cbase + rl + 1] - e0;

      auto flush = [&]() {
        Sb8[g * 80 + ((rl * 16 + m) ^ g)] = a;   // already f16 = MFMA format
        a = (half8)(_Float16)0;
      };
      auto bump = [&](int i) {    // advance cell state past edge index i
        while (i >= nend) {
          flush();
          ++rl;
          nend = (int)cofs_l[cbase + rl + 1] - e0;
        }
      };
      auto run_walk = [&](auto fetch) {
        for (int i = beg; i < endAll; i += 6) {
          const int nrem = endAll - i;
          half8 h0, h1, h2, h3, h4, h5;
          h0 = fetch(i);
          if (nrem > 1) h1 = fetch(i + 1);
          if (nrem > 2) h2 = fetch(i + 2);
          if (nrem > 3) h3 = fetch(i + 3);
          if (nrem > 4) h4 = fetch(i + 4);
          if (nrem > 5) h5 = fetch(i + 5);
          bump(i);      a += h0;          // 4x v_pk_add_f16
          if (nrem > 1) { bump(i + 1); a += h1; }
          if (nrem > 2) { bump(i + 2); a += h2; }
          if (nrem > 3) { bump(i + 3); a += h3; }
          if (nrem > 4) { bump(i + 4); a += h4; }
          if (nrem > 5) { bump(i + 5); a += h5; }
        }
        while (rl < rlB) { flush(); ++rl; }   // trailing (incl. empty) cells
      };

      if (use_lds) {
        run_walk([&](int i) {
          return *(const half8*)(hb + (size_t)spk[i] * DIM + mh8);
        });
      } else {   // overflow fallback (essentially never taken)
        run_walk([&](int i) {
          return *(const half8*)(hb + (size_t)es[e0 + i] * DIM + mh8);
        });
      }
    } else if (half == 0) {
      // self-loop mini-chunk: own row (feeds rel 20 = loop_w), slot 0
      half8 hv = *(const half8*)(hb + (size_t)(dst_base + g) * DIM + mh8);
      Sb8[g * 80 + (m ^ g)] = hv;   // already f16; sum of one row
    }
    __syncthreads();

    // ---- phase 2: nc-split 8 ways. wave w owns cols [16w,16w+16) ----
    const int rc = (c == 4) ? 1 : 5;
    for (int rl2 = 0; rl2 < rc; ++rl2) {
      const int r = (c == 4) ? (NRELP - 1) : (c * 5 + rl2);
      const unsigned short* bp =
          WP + ((((size_t)(layer * NRELP + r) * 4) * 8 + w) * 64 + lane) * 8;
#pragma unroll
      for (int ks = 0; ks < 4; ++ks) {
        half8 av = Sb8[m * 80 + ((rl2 * 16 + ks * 4 + quad) ^ m)];
        half8 bv = *(const half8*)(bp + (size_t)ks * 4096);
        acc = __builtin_amdgcn_mfma_f32_16x16x32_f16(av, bv, acc, 0, 0, 0);
      }
    }
    __syncthreads();
  }

  // ---- epilogue: wave w stores its 16-col tile; no cross-wave reduction ----
  const int col = w * 16 + m;
  const float bv = bias[col];
  if (outb) {
#pragma unroll
    for (int i = 0; i < 4; ++i)
      outb[(size_t)(dst_base + quad * 4 + i) * DIM + col] =
          f32_to_f16_raw(acc[i] + bv);
  } else {
#pragma unroll
    for (int i = 0; i < 4; ++i)
      outf[(size_t)(dst_base + quad * 4 + i) * DIM + col] = acc[i] + bv;
  }
}

// ---------------- launch ----------------
extern "C" void kernel_launch(void* const* d_in, const int* in_sizes, int n_in,
                              void* d_out, int out_size, void* d_ws, size_t ws_size,
                              hipStream_t stream) {
  const float* h0     = (const float*)d_in[0];
  const float* W      = (const float*)d_in[1];
  const float* loop_w = (const float*)d_in[2];
  const float* bias   = (const float*)d_in[3];
  const int* esrc     = (const int*)d_in[4];
  const int* edst     = (const int*)d_in[5];
  const int* etyp     = (const int*)d_in[6];
  float* out = (float*)d_out;

  char* ws = (char*)d_ws;
  size_t off = 0;
  auto alloc = [&](size_t bytes) -> void* {
    void* p = ws + off;
    off = (off + bytes + 255) & ~(size_t)255;
    return p;
  };
  unsigned short* hb0   = (unsigned short*)alloc((size_t)NN * DIM * 2);   // 12.8 MB
  unsigned short* hb1   = (unsigned short*)alloc((size_t)NN * DIM * 2);   // 12.8 MB
  unsigned short* WP    = (unsigned short*)alloc((size_t)PACKED_ELEMS * 2);
  unsigned int*   cnt   = (unsigned int*)alloc((size_t)CHB * NTILE * 4);  // 3.2 MB
  unsigned int*   csum  = (unsigned int*)alloc((size_t)NTILE * 4);
  unsigned int*   starts= (unsigned int*)alloc((size_t)(NTILE + 1) * 4);
  unsigned int*   ep    = (unsigned int*)alloc((size_t)NE * 4);           // 6.4 MB
  unsigned int*   cofs  = (unsigned int*)alloc((size_t)(CELLS + 1) * 4);  // 4 MB
  unsigned short* es    = (unsigned short*)alloc((size_t)NE * 2);         // 3.2 MB

  entry_kernel<<<CHB + CVT_BLKS + PKW_BLKS, 256, 0, stream>>>(
      edst, cnt, h0, hb0, W, loop_w, WP);
  colscan_kernel<<<(NTILE * 64 + 255) / 256, 256, 0, stream>>>(cnt, csum);
  scan1_kernel<<<1, 1024, 0, stream>>>(csum, starts);
  scatter_kernel<<<CHB, 256, 0, stream>>>(esrc, edst, etyp, starts, cnt, ep);
  tile_sort_kernel<<<NTILE, 512, 0, stream>>>(ep, starts, es, cofs);

  rgcn_layer_kernel<<<NTILE, 512, 0, stream>>>(hb0, WP, bias, 0, cofs, es,
                                               nullptr, hb1);
  rgcn_layer_kernel<<<NTILE, 512, 0, stream>>>(hb1, WP, bias + DIM, 1, cofs, es,
                                               out, nullptr);
}

// Round 16
// 369.613 us; speedup vs baseline: 6.7717x; 1.0690x over previous
//
#include <hip/hip_runtime.h>
#include <hip/hip_bf16.h>
#include <stdint.h>

// GNN_758: stacked RelGraphConv x2.  N=50000, E=1.6M, D=128, R=20.
// agg[dst] = sum_r (sum_{e in rel r -> dst} h[src]) @ W[r]; self-loop = rel 20.
// R23: tile_sort FUSED into layer 0. Layer-0 block b performs tile b's
// 320-bin sort in LDS (hist + Hillis-Steele scan -> cofs_l, rank -> spk
// directly -- no es/cofs global round-trip for itself), and emits es/cofs
// to global for layer 1 (unchanged proven read path). Deletes the tile_sort
// launch + ~13MB of round-trip traffic. Walk/MFMA core = R18 verbatim
// (frozen: 123.5us empirical floor; 10 structural alternatives all worse).
// Prep: entry(cnt|cvt|pack) -> colscan -> scan1 -> scatter -> [layer0+sort].

#define NN 50000
#define NE 1600000
#define DIM 128
#define NREL 20
#define NRELP 21
#define TILE 16
#define NTILE (NN / TILE)          // 3125 = tile bins
#define CELLS (NN * NREL)          // dst*20 + r
#define CHB 256                    // chunk blocks for count/scatter
#define CHE (NE / CHB)             // 6250 edges per chunk block
#define SPK_CAP 1024               // staged srcs per block (mean 512, sd ~23)
#define PACKED_ELEMS (2 * NRELP * 4 * 8 * 64 * 8)    // 688128
#define CVT_BLKS (NN * DIM / 4 / 256)                // 6250 (exact)
#define PKW_BLKS ((PACKED_ELEMS + 255) / 256)        // 2688

typedef __attribute__((ext_vector_type(8))) short short8;
typedef __attribute__((ext_vector_type(8))) _Float16 half8;
typedef __attribute__((ext_vector_type(4))) float f32x4;

__device__ __forceinline__ unsigned short f32_to_f16_raw(float f) {
  union { _Float16 h; unsigned short u; } c;
  c.h = (_Float16)f;               // v_cvt_f16_f32 (RNE)
  return c.u;
}

// ---------------- fused entry: cnt | cvt_f16 | pack_w ----------------
// blocks [0,CHB): tile hist.  [CHB,CHB+CVT_BLKS): h0->f16.  rest: pack W.
__global__ __launch_bounds__(256) void entry_kernel(
    const int* __restrict__ dst, unsigned int* __restrict__ cnt,
    const float* __restrict__ h0, unsigned short* __restrict__ hb0,
    const float* __restrict__ W, const float* __restrict__ loop_w,
    unsigned short* __restrict__ WP) {
  const int b = blockIdx.x;
  if (b < CHB) {
    // -- tile counting: bin = dst>>4, LDS-privatized, coalesced row write --
    __shared__ unsigned int h[NTILE];            // 12.5 KB
    for (int i = threadIdx.x; i < NTILE; i += 256) h[i] = 0u;
    __syncthreads();
    const int base = b * CHE;
    for (int i = base + threadIdx.x; i < base + CHE; i += 256)
      atomicAdd(&h[dst[i] >> 4], 1u);            // LDS atomic
    __syncthreads();
    unsigned int* row = cnt + (size_t)b * NTILE;
    for (int i = threadIdx.x; i < NTILE; i += 256) row[i] = h[i];
  } else if (b < CHB + CVT_BLKS) {
    // -- fp32 -> f16 (x4), nontemporal stores --
    const int i = (b - CHB) * 256 + threadIdx.x;   // < NN*DIM/4 exactly
    float4 f = ((const float4*)h0)[i];
    unsigned long long p =
        (unsigned long long)f32_to_f16_raw(f.x)
      | ((unsigned long long)f32_to_f16_raw(f.y) << 16)
      | ((unsigned long long)f32_to_f16_raw(f.z) << 32)
      | ((unsigned long long)f32_to_f16_raw(f.w) << 48);
    __builtin_nontemporal_store(p, (unsigned long long*)hb0 + i);
  } else {
    // -- pack W (+loop_w as rel 20) into B-fragment order, f16 --
    // WP flat: ((((l*21 + r)*4 + ks)*8 + nc)*64 + lane)*8  (verified R0/R1)
    const int idx = (b - CHB - CVT_BLKS) * 256 + threadIdx.x;
    if (idx >= PACKED_ELEMS) return;
    int j = idx & 7;       int t = idx >> 3;
    int lane = t & 63;     t >>= 6;
    int nc = t & 7;        t >>= 3;
    int ks = t & 3;        t >>= 2;
    int r = t % NRELP;     int l = t / NRELP;
    int k = ks * 32 + (lane >> 4) * 8 + j;
    int n = nc * 16 + (lane & 15);
    float v = (r < NREL) ? W[(((size_t)l * NREL + r) * DIM + k) * DIM + n]
                         : loop_w[((size_t)l * DIM + k) * DIM + n];
    WP[idx] = f32_to_f16_raw(v);
  }
}

// wave-per-bin exclusive prefix over the 256 chunk-blocks (in place) + totals.
__global__ __launch_bounds__(256) void colscan_kernel(
    unsigned int* __restrict__ cnt, unsigned int* __restrict__ csum) {
  const int b = (blockIdx.x * 256 + threadIdx.x) >> 6;   // bin = wave id
  const int lane = threadIdx.x & 63;
  if (b >= NTILE) return;
  unsigned int v[4], p[4], s = 0;
#pragma unroll
  for (int i = 0; i < 4; ++i) {
    v[i] = cnt[(size_t)(lane * 4 + i) * NTILE + b];
    p[i] = s; s += v[i];
  }
  unsigned int run = s;
  for (int d = 1; d < 64; d <<= 1) {
    unsigned int t = __shfl_up(run, d);
    if (lane >= d) run += t;
  }
  const unsigned int excl = run - s;     // exclusive prefix of this lane
#pragma unroll
  for (int i = 0; i < 4; ++i)
    cnt[(size_t)(lane * 4 + i) * NTILE + b] = excl + p[i];
  if (lane == 63) csum[b] = run;         // bin total
}

// single-block exclusive scan of csum[NTILE] -> starts[NTILE+1] (sentinel=NE)
__global__ __launch_bounds__(1024) void scan1_kernel(
    const unsigned int* __restrict__ csum, unsigned int* __restrict__ starts) {
  __shared__ unsigned int buf[1024];
  const int t = threadIdx.x;
  const int base = t * 4;
  unsigned int v[4], p[4], s = 0;
#pragma unroll
  for (int j = 0; j < 4; ++j) {
    v[j] = (base + j < NTILE) ? csum[base + j] : 0u;
    p[j] = s; s += v[j];
  }
  buf[t] = s;
  __syncthreads();
  for (int d = 1; d < 1024; d <<= 1) {
    unsigned int a = (t >= d) ? buf[t - d] : 0u;
    __syncthreads();
    buf[t] += a;
    __syncthreads();
  }
  unsigned int excl = buf[t] - s;
#pragma unroll
  for (int j = 0; j < 4; ++j)
    if (base + j < NTILE) starts[base + j] = excl + p[j];
  if (t == 1023) starts[NTILE] = buf[1023];      // = NE
}

// scatter to tile-sorted position. payload = src | dd<<16 | rel<<20 (5 bits).
__global__ __launch_bounds__(256) void scatter_kernel(
    const int* __restrict__ src, const int* __restrict__ dst,
    const int* __restrict__ et, const unsigned int* __restrict__ starts,
    const unsigned int* __restrict__ cnt, unsigned int* __restrict__ ep) {
  __shared__ unsigned int cur[NTILE];            // 12.5 KB
  const unsigned int* row = cnt + (size_t)blockIdx.x * NTILE;
  for (int i = threadIdx.x; i < NTILE; i += 256)
    cur[i] = starts[i] + row[i];
  __syncthreads();
  const int base = blockIdx.x * CHE;
  for (int i = base + threadIdx.x; i < base + CHE; i += 256) {
    int d = dst[i];
    unsigned int pos = atomicAdd(&cur[d >> 4], 1u);   // LDS atomic
    ep[pos] = (unsigned int)src[i] | ((unsigned int)(d & 15) << 16)
            | ((unsigned int)et[i] << 20);
  }
}

// ---------------- fused RGCN layer (R18 core, frozen; + optional sort) ----
// 3125 blocks x 512 threads (8 waves). LDS ~29.3KB -> 4 blocks/CU (wave cap).
// ep != null (layer 0): perform tile b's 320-bin sort in LDS (tile_sort
// verbatim), fill cofs_l/spk directly, emit es/cofs for layer 1.
// ep == null (layer 1): load cofs/es from global as before.
__global__ __launch_bounds__(512, 8) void rgcn_layer_kernel(
    const unsigned short* __restrict__ hb,    // [N,128] f16
    const unsigned short* __restrict__ WP,    // packed weights, f16
    const float* __restrict__ bias,           // [128] this layer
    int layer,
    unsigned int* __restrict__ cofs,          // [CELLS+1] cell offsets (io)
    unsigned short* __restrict__ es,          // [E] srcs, cell-sorted (io)
    const unsigned int* __restrict__ ep,      // [E] payload (layer 0) or null
    const unsigned int* __restrict__ startsg, // [NTILE+1] tile starts or null
    float* __restrict__ outf,                 // fp32 out (layer 1) or null
    unsigned short* __restrict__ outb)        // f16 out (layer 0) or null
{
  // Sb: [16 dst rows][5 rl slots * 16 slot16], slot16 = 8 f16 (16B),
  // slot index ^= (row & 15) -> conflict-free writes and reads (verified R8).
  __shared__ half8 Sb8[TILE * 80];           // 20480 B
  __shared__ unsigned int cofs_l[321];       // 1284 B
  __shared__ unsigned short spk[SPK_CAP];    // 2048 B
  __shared__ unsigned int esp_l[SPK_CAP];    // 4096 B (sort mode staging)
  __shared__ unsigned int hist[512];         // 2048 B (sort mode hist/scan)

  const int tid  = threadIdx.x;
  const int lane = tid & 63;
  const int w    = tid >> 6;        // wave 0..7
  const int quad = lane >> 4;
  const int m    = lane & 15;
  const int mh8  = m * 8;
  const int half = w >> 2;          // 0: rl{0,1}  1: rl{2,3,4}  (wave-uniform)
  const int g    = (w & 3) * 4 + quad;   // owned dst_local 0..15
  const int dst_base = blockIdx.x * TILE;

  int e0, etot;
  bool use_lds;
  if (ep) {
    // ---- fused tile sort (tile_sort logic verbatim, outputs stay in LDS) ----
    const unsigned int start = startsg[blockIdx.x];
    const unsigned int end   = startsg[blockIdx.x + 1];
    const int cnt = (int)(end - start);
    e0 = (int)start; etot = cnt;
    use_lds = (cnt <= SPK_CAP);
    hist[tid] = 0u;
    __syncthreads();
    if (use_lds) {
      for (int i = tid; i < cnt; i += 512) {
        unsigned int p = ep[start + i];
        esp_l[i] = p;
        atomicAdd(&hist[((p >> 16) & 15u) * 20u + (p >> 20)], 1u);
      }
    } else {  // overflow fallback (+22 sigma; effectively unreachable)
      for (int i = tid; i < cnt; i += 512) {
        unsigned int p = ep[start + i];
        atomicAdd(&hist[((p >> 16) & 15u) * 20u + (p >> 20)], 1u);
      }
    }
    __syncthreads();
    unsigned int own = hist[tid];
    for (int d = 1; d < 512; d <<= 1) {
      __syncthreads();
      unsigned int a = (tid >= d) ? hist[tid - d] : 0u;
      __syncthreads();
      hist[tid] += a;
    }
    __syncthreads();
    unsigned int excl = hist[tid] - own;   // local exclusive prefix
    hist[tid] = excl;                      // becomes rank cursor
    if (tid < 320) {
      cofs_l[tid] = start + excl;
      cofs[(size_t)blockIdx.x * 320 + tid] = start + excl;  // for layer 1
    }
    if (tid == 320) cofs_l[320] = end;
    if (blockIdx.x == NTILE - 1 && tid == 0) cofs[CELLS] = (unsigned int)NE;
    __syncthreads();
    for (int i = tid; i < cnt; i += 512) {
      unsigned int p = use_lds ? esp_l[i] : ep[start + i];
      int sub = (int)(((p >> 16) & 15u) * 20u + (p >> 20));
      unsigned int rk = atomicAdd(&hist[sub], 1u);   // local rank
      unsigned short s = (unsigned short)(p & 0xffffu);
      if (use_lds) spk[rk] = s;            // direct LDS staging, no round-trip
      es[start + rk] = s;                  // for layer 1
    }
    __syncthreads();
  } else {
    // ---- layer 1: load offsets + stage srcs from global (R18 path) ----
    for (int i = tid; i < 321; i += 512)
      cofs_l[i] = cofs[blockIdx.x * (TILE * NREL) + i];
    __syncthreads();
    e0 = (int)cofs_l[0];
    etot = (int)cofs_l[320] - e0;
    use_lds = (etot <= SPK_CAP);
    if (use_lds)
      for (int i = tid; i < etot; i += 512) spk[i] = es[e0 + i];
    __syncthreads();
  }

  f32x4 acc = (f32x4){0.f, 0.f, 0.f, 0.f};

  for (int c = 0; c < 5; ++c) {
    // ---- phase 1: merged-range walk, packed-f16 accumulate, batch-6 ----
    if (c < 4) {
      const int cbase = g * NREL + c * 5;
      const int rlA = half ? 2 : 0;
      const int rlB = half ? 5 : 2;
      const int beg    = (int)cofs_l[cbase + rlA] - e0;
      const int endAll = (int)cofs_l[cbase + rlB] - e0;

      half8 a = (half8)(_Float16)0;
      int rl = rlA;
      int nend = (int)cofs_l[cbase + rl + 1] - e0;

      auto flush = [&]() {
        Sb8[g * 80 + ((rl * 16 + m) ^ g)] = a;   // already f16 = MFMA format
        a = (half8)(_Float16)0;
      };
      auto bump = [&](int i) {    // advance cell state past edge index i
        while (i >= nend) {
          flush();
          ++rl;
          nend = (int)cofs_l[cbase + rl + 1] - e0;
        }
      };
      auto run_walk = [&](auto fetch) {
        for (int i = beg; i < endAll; i += 6) {
          const int nrem = endAll - i;
          half8 h0, h1, h2, h3, h4, h5;
          h0 = fetch(i);
          if (nrem > 1) h1 = fetch(i + 1);
          if (nrem > 2) h2 = fetch(i + 2);
          if (nrem > 3) h3 = fetch(i + 3);
          if (nrem > 4) h4 = fetch(i + 4);
          if (nrem > 5) h5 = fetch(i + 5);
          bump(i);      a += h0;          // 4x v_pk_add_f16
          if (nrem > 1) { bump(i + 1); a += h1; }
          if (nrem > 2) { bump(i + 2); a += h2; }
          if (nrem > 3) { bump(i + 3); a += h3; }
          if (nrem > 4) { bump(i + 4); a += h4; }
          if (nrem > 5) { bump(i + 5); a += h5; }
        }
        while (rl < rlB) { flush(); ++rl; }   // trailing (incl. empty) cells
      };

      if (use_lds) {
        run_walk([&](int i) {
          return *(const half8*)(hb + (size_t)spk[i] * DIM + mh8);
        });
      } else {   // overflow fallback (essentially never taken)
        run_walk([&](int i) {
          return *(const half8*)(hb + (size_t)es[e0 + i] * DIM + mh8);
        });
      }
    } else if (half == 0) {
      // self-loop mini-chunk: own row (feeds rel 20 = loop_w), slot 0
      half8 hv = *(const half8*)(hb + (size_t)(dst_base + g) * DIM + mh8);
      Sb8[g * 80 + (m ^ g)] = hv;   // already f16; sum of one row
    }
    __syncthreads();

    // ---- phase 2: nc-split 8 ways. wave w owns cols [16w,16w+16) ----
    const int rc = (c == 4) ? 1 : 5;
    for (int rl2 = 0; rl2 < rc; ++rl2) {
      const int r = (c == 4) ? (NRELP - 1) : (c * 5 + rl2);
      const unsigned short* bp =
          WP + ((((size_t)(layer * NRELP + r) * 4) * 8 + w) * 64 + lane) * 8;
#pragma unroll
      for (int ks = 0; ks < 4; ++ks) {
        half8 av = Sb8[m * 80 + ((rl2 * 16 + ks * 4 + quad) ^ m)];
        half8 bv = *(const half8*)(bp + (size_t)ks * 4096);
        acc = __builtin_amdgcn_mfma_f32_16x16x32_f16(av, bv, acc, 0, 0, 0);
      }
    }
    __syncthreads();
  }

  // ---- epilogue: wave w stores its 16-col tile; no cross-wave reduction ----
  const int col = w * 16 + m;
  const float bv = bias[col];
  if (outb) {
#pragma unroll
    for (int i = 0; i < 4; ++i)
      outb[(size_t)(dst_base + quad * 4 + i) * DIM + col] =
          f32_to_f16_raw(acc[i] + bv);
  } else {
#pragma unroll
    for (int i = 0; i < 4; ++i)
      outf[(size_t)(dst_base + quad * 4 + i) * DIM + col] = acc[i] + bv;
  }
}

// ---------------- launch ----------------
extern "C" void kernel_launch(void* const* d_in, const int* in_sizes, int n_in,
                              void* d_out, int out_size, void* d_ws, size_t ws_size,
                              hipStream_t stream) {
  const float* h0     = (const float*)d_in[0];
  const float* W      = (const float*)d_in[1];
  const float* loop_w = (const float*)d_in[2];
  const float* bias   = (const float*)d_in[3];
  const int* esrc     = (const int*)d_in[4];
  const int* edst     = (const int*)d_in[5];
  const int* etyp     = (const int*)d_in[6];
  float* out = (float*)d_out;

  char* ws = (char*)d_ws;
  size_t off = 0;
  auto alloc = [&](size_t bytes) -> void* {
    void* p = ws + off;
    off = (off + bytes + 255) & ~(size_t)255;
    return p;
  };
  unsigned short* hb0   = (unsigned short*)alloc((size_t)NN * DIM * 2);   // 12.8 MB
  unsigned short* hb1   = (unsigned short*)alloc((size_t)NN * DIM * 2);   // 12.8 MB
  unsigned short* WP    = (unsigned short*)alloc((size_t)PACKED_ELEMS * 2);
  unsigned int*   cnt   = (unsigned int*)alloc((size_t)CHB * NTILE * 4);  // 3.2 MB
  unsigned int*   csum  = (unsigned int*)alloc((size_t)NTILE * 4);
  unsigned int*   starts= (unsigned int*)alloc((size_t)(NTILE + 1) * 4);
  unsigned int*   ep    = (unsigned int*)alloc((size_t)NE * 4);           // 6.4 MB
  unsigned int*   cofs  = (unsigned int*)alloc((size_t)(CELLS + 1) * 4);  // 4 MB
  unsigned short* es    = (unsigned short*)alloc((size_t)NE * 2);         // 3.2 MB

  entry_kernel<<<CHB + CVT_BLKS + PKW_BLKS, 256, 0, stream>>>(
      edst, cnt, h0, hb0, W, loop_w, WP);
  colscan_kernel<<<(NTILE * 64 + 255) / 256, 256, 0, stream>>>(cnt, csum);
  scan1_kernel<<<1, 1024, 0, stream>>>(csum, starts);
  scatter_kernel<<<CHB, 256, 0, stream>>>(esrc, edst, etyp, starts, cnt, ep);

  rgcn_layer_kernel<<<NTILE, 512, 0, stream>>>(hb0, WP, bias, 0, cofs, es,
                                               ep, starts, nullptr, hb1);
  rgcn_layer_kernel<<<NTILE, 512, 0, stream>>>(hb1, WP, bias + DIM, 1, cofs, es,
                                               nullptr, nullptr, out, nullptr);
}